// Round 6
// baseline (286.639 us; speedup 1.0000x reference)
//
#include <hip/hip_runtime.h>
#include <hip/hip_bf16.h>

#define NATC 10000
#define NNC 32
#define RSNC 16
#define THETANC 8
#define NEMBC 4
#define FEATC 576

typedef __attribute__((ext_vector_type(8))) short short8;  // 8 bf16 (4 VGPRs)
typedef __attribute__((ext_vector_type(4))) float f32x4;

static __device__ __forceinline__ short f2bf(float x) {
    union { __hip_bfloat16 h; short s; } u;
    u.h = __float2bfloat16(x);
    return u.s;
}

// ---------------------------------------------------------------------------
// Kernel 0: pack W1 (576x64) and W2 (64x64) into bf16 MFMA B-fragment order,
// and zero the completion counter (stream-ordered before desc_kernel).
// B-frag (16x16x32): lane l supplies W[k = ks*32 + (l>>4)*8 + jj][n = nt*16 + (l&15)]
// stored Wp[((ks*4+nt)*64 + l)*8 + jj].  W1: 18 ks; W2: 2 ks.
// ---------------------------------------------------------------------------
__global__ __launch_bounds__(256) void prep_kernel(
    const float* __restrict__ W1, const float* __restrict__ W2,
    ushort* __restrict__ W1p, ushort* __restrict__ W2p,
    unsigned int* __restrict__ counter)
{
    const int gid = blockIdx.x * 256 + threadIdx.x;   // 0..5119
    if (gid == 0) *counter = 0u;
    const float* W = (gid < 4608) ? W1 : W2;
    ushort* Wp = (gid < 4608) ? W1p : W2p;
    const int g = (gid < 4608) ? gid : gid - 4608;
    const int l = g & 63, ntks = g >> 6;
    const int nt = ntks & 3, ks = ntks >> 2;
    const int q = l >> 4, c = l & 15;
    ushort pk[8];
    #pragma unroll
    for (int jj = 0; jj < 8; ++jj)
        pk[jj] = (ushort)f2bf(W[(ks * 32 + q * 8 + jj) * 64 + nt * 16 + c]);
    #pragma unroll
    for (int jj = 0; jj < 8; ++jj) Wp[g * 8 + jj] = pk[jj];
}

// ---------------------------------------------------------------------------
// Kernel 1: FUSED descriptor + MLP + tail total-energy reduction.
// One block (256 thr = 4 waves) per atom.
//  - cosm/sinm row stride 36 floats (144 B, 16B-aligned): phase-4 A-build
//    reads are ds_read_b128 (16/thread instead of 64 ds_read_b32).
//  - layer1 AND layer2 via m=1 MFMA (W1p/W2p B-frags from prep).
//  - each block stores e_atom[i]; last-to-finish block (device-scope counter)
//    reduces all 10000 energies -> out[0]. Two dispatches total.
// LDS ~26.8 KB -> 6 blocks/CU possible.
// ---------------------------------------------------------------------------
__global__ __launch_bounds__(256, 4) void desc_kernel(
    const float* __restrict__ pos,
    const float* __restrict__ spe,
    const float* __restrict__ theta_s,
    const float* __restrict__ kn_rad,
    const int* __restrict__ nidx,
    const ushort* __restrict__ W1p,
    const float* __restrict__ b1,
    const ushort* __restrict__ W2p,
    const float* __restrict__ b2,
    const float* __restrict__ W3,
    const float* __restrict__ b3,
    float* __restrict__ e_atom,
    unsigned int* __restrict__ counter,
    float* __restrict__ out)
{
    constexpr float RC = 5.0f;
    constexpr float PI_F = 3.14159265358979323846f;
    constexpr float PREF = 3.0517578125e-05f; // 2^(1-16)

    __shared__ __attribute__((aligned(16))) float ux[NNC], uy[NNC], uz[NNC];
    __shared__ __attribute__((aligned(16))) float rbase[NNC], rw[NNC];
    __shared__ __attribute__((aligned(16))) float bfs[NNC * 17];
    __shared__ __attribute__((aligned(16))) float ses[NNC * 5];
    __shared__ __attribute__((aligned(16))) float P[NNC * 66];      // fp32, pad 66
    __shared__ __attribute__((aligned(16))) float cosm[NNC * 36];   // 144B rows
    __shared__ __attribute__((aligned(16))) float sinm[NNC * 36];
    __shared__ __attribute__((aligned(16))) short Pb[4 * 64 * 8];   // bf16 B-frags
    __shared__ __attribute__((aligned(16))) ushort drow[FEATC];     // bf16 desc row
    __shared__ __attribute__((aligned(16))) float h1p[64];          // layer1 pre-act
    __shared__ __attribute__((aligned(16))) ushort h1b[64];         // tanh(h1) bf16
    __shared__ float red[4];
    __shared__ int lastflag;

    const int i   = blockIdx.x;
    const int tid = threadIdx.x;

    // --- phase 0: bond geometry (32 threads) ---
    if (tid < NNC) {
        const int j = tid;
        const int n = nidx[i * NNC + j];
        const float pix = pos[i * 3 + 0], piy = pos[i * 3 + 1], piz = pos[i * 3 + 2];
        const float dx = pos[n * 3 + 0] - pix;
        const float dy = pos[n * 3 + 1] - piy;
        const float dz = pos[n * 3 + 2] - piz;
        const float r = sqrtf(dx * dx + dy * dy + dz * dz) + 1e-8f;
        const float inv = 1.0f / r;
        ux[j] = dx * inv; uy[j] = dy * inv; uz[j] = dz * inv;
        const float fc = (r < RC) ? 0.5f * (cosf(PI_F * r * (1.0f / RC)) + 1.0f) : 0.0f;
        rbase[j] = sqrtf(2.0f / RC) * inv * fc;
        rw[j]    = (PI_F / RC) * kn_rad[0] * r;
        #pragma unroll
        for (int m = 0; m < NEMBC; ++m)
            ses[j * 5 + m] = spe[n * NEMBC + m] * spe[i * NEMBC + m];
    }
    __syncthreads();

    // --- phase 1: bessel basis (512 items) ---
    #pragma unroll
    for (int k = 0; k < 2; ++k) {
        const int e = tid + k * 256;
        const int j = e >> 4, l = e & 15;
        bfs[j * 17 + l] = rbase[j] * sinf(rw[j] * (float)(l + 1));
    }
    __syncthreads();

    // --- phase 2: P fp32 (stride 66) + cos/sin matrix (stride 36) ---
    #pragma unroll
    for (int k = 0; k < 8; ++k) {
        const int e = tid + k * 256;
        const int j = e >> 6, p = e & 63;
        P[j * 66 + p] = bfs[j * 17 + (p >> 2)] * ses[j * 5 + (p & 3)];
    }
    #pragma unroll
    for (int k = 0; k < 4; ++k) {
        const int idx = tid + k * 256;
        const int j = idx >> 5, kk = idx & 31;
        float c = ux[j] * ux[kk] + uy[j] * uy[kk] + uz[j] * uz[kk];
        c = fminf(fmaxf(c, -1.0f + 1e-6f), 1.0f - 1e-6f);
        cosm[j * 36 + kk] = c;
        sinm[j * 36 + kk] = sqrtf(fmaxf(1.0f - c * c, 0.0f));
    }
    __syncthreads();

    // --- phase 3: pack Pb (bf16 B-frags) + radial descriptor into drow ---
    {
        const int nt = tid >> 6, l2 = tid & 63;
        const int q2 = l2 >> 4, c2 = l2 & 15;
        short8 pk;
        #pragma unroll
        for (int jj = 0; jj < 8; ++jj)
            pk[jj] = f2bf(P[(q2 * 8 + jj) * 66 + nt * 16 + c2]);
        *(short8*)&Pb[(nt * 64 + l2) * 8] = pk;
    }
    if (tid < 64) {
        float s = 0.0f;
        #pragma unroll 8
        for (int j = 0; j < NNC; ++j) s += P[j * 66 + tid];
        drow[tid] = (ushort)f2bf(s);
    }
    __syncthreads();

    // --- phase 4: MFMA angular contraction per theta ---
    const int w = tid >> 6, l = tid & 63;
    const int q = l >> 4, c = l & 15;

    for (int tt = 0; tt < 2; ++tt) {
        const int t = w + tt * 4;
        const float th = theta_s[t];
        const float ct = cosf(th), st = sinf(th);

        short8 afr[2];
        #pragma unroll
        for (int mt = 0; mt < 2; ++mt) {
            const int kk = mt * 16 + c;
            const float4 c0 = *(const float4*)&cosm[kk * 36 + q * 8];
            const float4 c1 = *(const float4*)&cosm[kk * 36 + q * 8 + 4];
            const float4 s0 = *(const float4*)&sinm[kk * 36 + q * 8];
            const float4 s1 = *(const float4*)&sinm[kk * 36 + q * 8 + 4];
            float cv[8], sv[8];
            cv[0]=c0.x; cv[1]=c0.y; cv[2]=c0.z; cv[3]=c0.w;
            cv[4]=c1.x; cv[5]=c1.y; cv[6]=c1.z; cv[7]=c1.w;
            sv[0]=s0.x; sv[1]=s0.y; sv[2]=s0.z; sv[3]=s0.w;
            sv[4]=s1.x; sv[5]=s1.y; sv[6]=s1.z; sv[7]=s1.w;
            #pragma unroll
            for (int jj = 0; jj < 8; ++jj) {
                const float cosd = fmaf(cv[jj], ct, sv[jj] * st);
                const float x = 1.0f + cosd;
                const float x2 = x * x, x4 = x2 * x2, x8 = x4 * x4;
                afr[mt][jj] = f2bf(PREF * (x8 * x8));
            }
        }

        f32x4 acc[2][4];
        #pragma unroll
        for (int mt = 0; mt < 2; ++mt)
            #pragma unroll
            for (int nt = 0; nt < 4; ++nt)
                acc[mt][nt] = (f32x4){0.0f, 0.0f, 0.0f, 0.0f};

        #pragma unroll
        for (int nt = 0; nt < 4; ++nt) {
            const short8 bfr = *(const short8*)&Pb[(nt * 64 + l) * 8];
            acc[0][nt] = __builtin_amdgcn_mfma_f32_16x16x32_bf16(afr[0], bfr, acc[0][nt], 0, 0, 0);
            acc[1][nt] = __builtin_amdgcn_mfma_f32_16x16x32_bf16(afr[1], bfr, acc[1][nt], 0, 0, 0);
        }

        float pt[4];
        #pragma unroll
        for (int nt = 0; nt < 4; ++nt) {
            float s = 0.0f;
            #pragma unroll
            for (int mt = 0; mt < 2; ++mt)
                #pragma unroll
                for (int r = 0; r < 4; ++r) {
                    const int kk = mt * 16 + q * 4 + r;
                    s = fmaf(acc[mt][nt][r], P[kk * 66 + nt * 16 + c], s);
                }
            s += __shfl_xor(s, 16, 64);
            s += __shfl_xor(s, 32, 64);
            pt[nt] = s;
        }
        const float v = (q == 0) ? pt[0] : (q == 1) ? pt[1] : (q == 2) ? pt[2] : pt[3];
        drow[64 + t * 64 + l] = (ushort)f2bf(v);
    }
    __syncthreads();

    // --- phase 5: layer1 via m=1 MFMA (wave w = n-tile) ---
    {
        f32x4 acc1 = (f32x4){0.0f, 0.0f, 0.0f, 0.0f};
        const short8 zero8 = (short8){0, 0, 0, 0, 0, 0, 0, 0};
        #pragma unroll 3
        for (int ks = 0; ks < 18; ++ks) {
            const short8 bfr = *(const short8*)&W1p[((ks * 4 + w) * 64 + l) * 8];
            short8 afr = *(const short8*)&drow[ks * 32 + q * 8];
            if (c != 0) afr = zero8;          // only A row 0 is real
            acc1 = __builtin_amdgcn_mfma_f32_16x16x32_bf16(afr, bfr, acc1, 0, 0, 0);
        }
        if (l < 16) h1p[w * 16 + l] = acc1[0];   // D row 0
    }
    __syncthreads();

    // --- phase 6: tanh -> bf16 h1, then layer2 via m=1 MFMA ---
    if (tid < 64) h1b[tid] = (ushort)f2bf(tanhf(h1p[tid] + b1[tid]));
    __syncthreads();
    {
        f32x4 acc2 = (f32x4){0.0f, 0.0f, 0.0f, 0.0f};
        const short8 zero8 = (short8){0, 0, 0, 0, 0, 0, 0, 0};
        #pragma unroll
        for (int ks = 0; ks < 2; ++ks) {
            const short8 bfr = *(const short8*)&W2p[((ks * 4 + w) * 64 + l) * 8];
            short8 afr = *(const short8*)&h1b[ks * 32 + q * 8];
            if (c != 0) afr = zero8;
            acc2 = __builtin_amdgcn_mfma_f32_16x16x32_bf16(afr, bfr, acc2, 0, 0, 0);
        }
        // layer 3 partial on lanes l<16 (D row 0): n = w*16 + l
        float s = 0.0f;
        if (l < 16) s = tanhf(acc2[0] + b2[w * 16 + l]) * W3[w * 16 + l];
        s += __shfl_xor(s, 1, 64);
        s += __shfl_xor(s, 2, 64);
        s += __shfl_xor(s, 4, 64);
        s += __shfl_xor(s, 8, 64);
        if (l == 0) red[w] = s;
    }
    __syncthreads();

    // --- phase 7: store e_atom; last-finishing block reduces everything ---
    if (tid == 0) {
        e_atom[i] = (red[0] + red[1]) + (red[2] + red[3]) + b3[0];
        __threadfence();                       // make e_atom store visible
        const unsigned int old = atomicAdd(counter, 1u);
        lastflag = (old == (unsigned int)(NATC - 1)) ? 1 : 0;
    }
    __syncthreads();
    if (lastflag) {
        __threadfence();                       // acquire: see all e_atom stores
        float s = 0.0f;
        for (int idx = tid; idx < NATC / 4; idx += 256) {
            const float4 v = *(const float4*)&e_atom[idx * 4];
            s += (v.x + v.y) + (v.z + v.w);
        }
        #pragma unroll
        for (int off = 1; off <= 32; off <<= 1)
            s += __shfl_xor(s, off, 64);
        if ((tid & 63) == 0) red[tid >> 6] = s;
        __syncthreads();
        if (tid == 0) out[0] = (red[0] + red[1]) + (red[2] + red[3]);
    }
}

extern "C" void kernel_launch(void* const* d_in, const int* in_sizes, int n_in,
                              void* d_out, int out_size, void* d_ws, size_t ws_size,
                              hipStream_t stream)
{
    const float* pos   = (const float*)d_in[0];
    const float* spe   = (const float*)d_in[1];
    const float* theta = (const float*)d_in[2];
    const float* kn    = (const float*)d_in[3];
    const float* W1    = (const float*)d_in[4];
    const float* b1    = (const float*)d_in[5];
    const float* W2    = (const float*)d_in[6];
    const float* b2    = (const float*)d_in[7];
    const float* W3    = (const float*)d_in[8];
    const float* b3    = (const float*)d_in[9];
    const int*   nidx  = (const int*)d_in[10];
    float* out = (float*)d_out;

    // workspace: e_atom [10000 f32, 16B-aligned] | W1p [4608*8 u16] | W2p [512*8 u16] | counter [u32]
    float*        e_atom  = (float*)d_ws;
    ushort*       W1p     = (ushort*)((char*)d_ws + 40064);
    ushort*       W2p     = W1p + 4608 * 8;
    unsigned int* counter = (unsigned int*)(W2p + 512 * 8);

    prep_kernel<<<20, 256, 0, stream>>>(W1, W2, W1p, W2p, counter);
    desc_kernel<<<NATC, 256, 0, stream>>>(pos, spe, theta, kn, nidx,
                                          W1p, b1, W2p, b2, W3, b3,
                                          e_atom, counter, out);
}

// Round 7
// 211.935 us; speedup vs baseline: 1.3525x; 1.3525x over previous
//
#include <hip/hip_runtime.h>
#include <hip/hip_bf16.h>

#define NATC 10000
#define NNC 32
#define RSNC 16
#define THETANC 8
#define NEMBC 4
#define FEATC 576

typedef __attribute__((ext_vector_type(8))) short short8;  // 8 bf16 (4 VGPRs)
typedef __attribute__((ext_vector_type(4))) float f32x4;

static __device__ __forceinline__ short f2bf(float x) {
    union { __hip_bfloat16 h; short s; } u;
    u.h = __float2bfloat16(x);
    return u.s;
}

// ---------------------------------------------------------------------------
// SINGLE fused kernel: descriptor + MLP + atomic energy accumulation.
// One block (256 thr = 4 waves) per atom.
//  - W1/W2 MFMA B-fragments built on the fly from fp32 weights (L2-resident,
//    coalesced 64B segments per quad-row) — no prep dispatch.
//  - per-block energy -> one fire-and-forget atomicAdd(out) (no fence, no
//    counter: round-6's device-fence pattern collapsed VALUBusy to 25%).
// LDS ~26.8 KB -> 6 blocks/CU.
// ---------------------------------------------------------------------------
__global__ __launch_bounds__(256, 4) void desc_kernel(
    const float* __restrict__ pos,
    const float* __restrict__ spe,
    const float* __restrict__ theta_s,
    const float* __restrict__ kn_rad,
    const int* __restrict__ nidx,
    const float* __restrict__ W1,
    const float* __restrict__ b1,
    const float* __restrict__ W2,
    const float* __restrict__ b2,
    const float* __restrict__ W3,
    const float* __restrict__ b3,
    float* __restrict__ out)
{
    constexpr float RC = 5.0f;
    constexpr float PI_F = 3.14159265358979323846f;
    constexpr float PREF = 3.0517578125e-05f; // 2^(1-16)

    __shared__ __attribute__((aligned(16))) float ux[NNC], uy[NNC], uz[NNC];
    __shared__ __attribute__((aligned(16))) float rbase[NNC], rw[NNC];
    __shared__ __attribute__((aligned(16))) float bfs[NNC * 17];
    __shared__ __attribute__((aligned(16))) float ses[NNC * 5];
    __shared__ __attribute__((aligned(16))) float P[NNC * 66];      // fp32, pad 66
    __shared__ __attribute__((aligned(16))) float cosm[NNC * 36];   // 144B rows
    __shared__ __attribute__((aligned(16))) float sinm[NNC * 36];
    __shared__ __attribute__((aligned(16))) short Pb[4 * 64 * 8];   // bf16 B-frags
    __shared__ __attribute__((aligned(16))) ushort drow[FEATC];     // bf16 desc row
    __shared__ __attribute__((aligned(16))) float h1p[64];          // layer1 pre-act
    __shared__ __attribute__((aligned(16))) ushort h1b[64];         // tanh(h1) bf16
    __shared__ float red[4];

    const int i   = blockIdx.x;
    const int tid = threadIdx.x;

    // --- phase 0: bond geometry (32 threads) ---
    if (tid < NNC) {
        const int j = tid;
        const int n = nidx[i * NNC + j];
        const float pix = pos[i * 3 + 0], piy = pos[i * 3 + 1], piz = pos[i * 3 + 2];
        const float dx = pos[n * 3 + 0] - pix;
        const float dy = pos[n * 3 + 1] - piy;
        const float dz = pos[n * 3 + 2] - piz;
        const float r = sqrtf(dx * dx + dy * dy + dz * dz) + 1e-8f;
        const float inv = 1.0f / r;
        ux[j] = dx * inv; uy[j] = dy * inv; uz[j] = dz * inv;
        const float fc = (r < RC) ? 0.5f * (cosf(PI_F * r * (1.0f / RC)) + 1.0f) : 0.0f;
        rbase[j] = sqrtf(2.0f / RC) * inv * fc;
        rw[j]    = (PI_F / RC) * kn_rad[0] * r;
        #pragma unroll
        for (int m = 0; m < NEMBC; ++m)
            ses[j * 5 + m] = spe[n * NEMBC + m] * spe[i * NEMBC + m];
    }
    __syncthreads();

    // --- phase 1: bessel basis (512 items) ---
    #pragma unroll
    for (int k = 0; k < 2; ++k) {
        const int e = tid + k * 256;
        const int j = e >> 4, l = e & 15;
        bfs[j * 17 + l] = rbase[j] * sinf(rw[j] * (float)(l + 1));
    }
    __syncthreads();

    // --- phase 2: P fp32 (stride 66) + cos/sin matrix (stride 36) ---
    #pragma unroll
    for (int k = 0; k < 8; ++k) {
        const int e = tid + k * 256;
        const int j = e >> 6, p = e & 63;
        P[j * 66 + p] = bfs[j * 17 + (p >> 2)] * ses[j * 5 + (p & 3)];
    }
    #pragma unroll
    for (int k = 0; k < 4; ++k) {
        const int idx = tid + k * 256;
        const int j = idx >> 5, kk = idx & 31;
        float c = ux[j] * ux[kk] + uy[j] * uy[kk] + uz[j] * uz[kk];
        c = fminf(fmaxf(c, -1.0f + 1e-6f), 1.0f - 1e-6f);
        cosm[j * 36 + kk] = c;
        sinm[j * 36 + kk] = sqrtf(fmaxf(1.0f - c * c, 0.0f));
    }
    __syncthreads();

    // --- phase 3: pack Pb (bf16 B-frags) + radial descriptor into drow ---
    {
        const int nt = tid >> 6, l2 = tid & 63;
        const int q2 = l2 >> 4, c2 = l2 & 15;
        short8 pk;
        #pragma unroll
        for (int jj = 0; jj < 8; ++jj)
            pk[jj] = f2bf(P[(q2 * 8 + jj) * 66 + nt * 16 + c2]);
        *(short8*)&Pb[(nt * 64 + l2) * 8] = pk;
    }
    if (tid < 64) {
        float s = 0.0f;
        #pragma unroll 8
        for (int j = 0; j < NNC; ++j) s += P[j * 66 + tid];
        drow[tid] = (ushort)f2bf(s);
    }
    __syncthreads();

    // --- phase 4: MFMA angular contraction per theta ---
    const int w = tid >> 6, l = tid & 63;
    const int q = l >> 4, c = l & 15;

    for (int tt = 0; tt < 2; ++tt) {
        const int t = w + tt * 4;
        const float th = theta_s[t];
        const float ct = cosf(th), st = sinf(th);

        short8 afr[2];
        #pragma unroll
        for (int mt = 0; mt < 2; ++mt) {
            const int kk = mt * 16 + c;
            const float4 c0 = *(const float4*)&cosm[kk * 36 + q * 8];
            const float4 c1 = *(const float4*)&cosm[kk * 36 + q * 8 + 4];
            const float4 s0 = *(const float4*)&sinm[kk * 36 + q * 8];
            const float4 s1 = *(const float4*)&sinm[kk * 36 + q * 8 + 4];
            float cv[8], sv[8];
            cv[0]=c0.x; cv[1]=c0.y; cv[2]=c0.z; cv[3]=c0.w;
            cv[4]=c1.x; cv[5]=c1.y; cv[6]=c1.z; cv[7]=c1.w;
            sv[0]=s0.x; sv[1]=s0.y; sv[2]=s0.z; sv[3]=s0.w;
            sv[4]=s1.x; sv[5]=s1.y; sv[6]=s1.z; sv[7]=s1.w;
            #pragma unroll
            for (int jj = 0; jj < 8; ++jj) {
                const float cosd = fmaf(cv[jj], ct, sv[jj] * st);
                const float x = 1.0f + cosd;
                const float x2 = x * x, x4 = x2 * x2, x8 = x4 * x4;
                afr[mt][jj] = f2bf(PREF * (x8 * x8));
            }
        }

        f32x4 acc[2][4];
        #pragma unroll
        for (int mt = 0; mt < 2; ++mt)
            #pragma unroll
            for (int nt = 0; nt < 4; ++nt)
                acc[mt][nt] = (f32x4){0.0f, 0.0f, 0.0f, 0.0f};

        #pragma unroll
        for (int nt = 0; nt < 4; ++nt) {
            const short8 bfr = *(const short8*)&Pb[(nt * 64 + l) * 8];
            acc[0][nt] = __builtin_amdgcn_mfma_f32_16x16x32_bf16(afr[0], bfr, acc[0][nt], 0, 0, 0);
            acc[1][nt] = __builtin_amdgcn_mfma_f32_16x16x32_bf16(afr[1], bfr, acc[1][nt], 0, 0, 0);
        }

        float pt[4];
        #pragma unroll
        for (int nt = 0; nt < 4; ++nt) {
            float s = 0.0f;
            #pragma unroll
            for (int mt = 0; mt < 2; ++mt)
                #pragma unroll
                for (int r = 0; r < 4; ++r) {
                    const int kk = mt * 16 + q * 4 + r;
                    s = fmaf(acc[mt][nt][r], P[kk * 66 + nt * 16 + c], s);
                }
            s += __shfl_xor(s, 16, 64);
            s += __shfl_xor(s, 32, 64);
            pt[nt] = s;
        }
        const float v = (q == 0) ? pt[0] : (q == 1) ? pt[1] : (q == 2) ? pt[2] : pt[3];
        drow[64 + t * 64 + l] = (ushort)f2bf(v);
    }
    __syncthreads();

    // --- phase 5: layer1 via m=1 MFMA; W1 B-frags built on the fly ---
    // lane l supplies B[k = ks*32 + q*8 + jj][n = w*16 + c] from fp32 W1.
    {
        f32x4 acc1 = (f32x4){0.0f, 0.0f, 0.0f, 0.0f};
        const short8 zero8 = (short8){0, 0, 0, 0, 0, 0, 0, 0};
        const float* Wbase = &W1[(q * 8) * 64 + w * 16 + c];
        #pragma unroll 3
        for (int ks = 0; ks < 18; ++ks) {
            short8 bfr;
            #pragma unroll
            for (int jj = 0; jj < 8; ++jj)
                bfr[jj] = f2bf(Wbase[(ks * 32 + jj) * 64]);
            short8 afr = *(const short8*)&drow[ks * 32 + q * 8];
            if (c != 0) afr = zero8;          // only A row 0 is real
            acc1 = __builtin_amdgcn_mfma_f32_16x16x32_bf16(afr, bfr, acc1, 0, 0, 0);
        }
        if (l < 16) h1p[w * 16 + l] = acc1[0];   // D row 0
    }
    __syncthreads();

    // --- phase 6: tanh -> bf16 h1, layer2 via m=1 MFMA (W2 on the fly) ---
    if (tid < 64) h1b[tid] = (ushort)f2bf(tanhf(h1p[tid] + b1[tid]));
    __syncthreads();
    {
        f32x4 acc2 = (f32x4){0.0f, 0.0f, 0.0f, 0.0f};
        const short8 zero8 = (short8){0, 0, 0, 0, 0, 0, 0, 0};
        const float* Wbase = &W2[(q * 8) * 64 + w * 16 + c];
        #pragma unroll
        for (int ks = 0; ks < 2; ++ks) {
            short8 bfr;
            #pragma unroll
            for (int jj = 0; jj < 8; ++jj)
                bfr[jj] = f2bf(Wbase[(ks * 32 + jj) * 64]);
            short8 afr = *(const short8*)&h1b[ks * 32 + q * 8];
            if (c != 0) afr = zero8;
            acc2 = __builtin_amdgcn_mfma_f32_16x16x32_bf16(afr, bfr, acc2, 0, 0, 0);
        }
        // layer 3 partial on lanes l<16 (D row 0): n = w*16 + l
        float s = 0.0f;
        if (l < 16) s = tanhf(acc2[0] + b2[w * 16 + l]) * W3[w * 16 + l];
        s += __shfl_xor(s, 1, 64);
        s += __shfl_xor(s, 2, 64);
        s += __shfl_xor(s, 4, 64);
        s += __shfl_xor(s, 8, 64);
        if (l == 0) red[w] = s;
    }
    __syncthreads();

    // --- phase 7: one fire-and-forget atomic per block ---
    if (tid == 0)
        atomicAdd(out, (red[0] + red[1]) + (red[2] + red[3]) + b3[0]);
}

extern "C" void kernel_launch(void* const* d_in, const int* in_sizes, int n_in,
                              void* d_out, int out_size, void* d_ws, size_t ws_size,
                              hipStream_t stream)
{
    const float* pos   = (const float*)d_in[0];
    const float* spe   = (const float*)d_in[1];
    const float* theta = (const float*)d_in[2];
    const float* kn    = (const float*)d_in[3];
    const float* W1    = (const float*)d_in[4];
    const float* b1    = (const float*)d_in[5];
    const float* W2    = (const float*)d_in[6];
    const float* b2    = (const float*)d_in[7];
    const float* W3    = (const float*)d_in[8];
    const float* b3    = (const float*)d_in[9];
    const int*   nidx  = (const int*)d_in[10];
    float* out = (float*)d_out;

    hipMemsetAsync(out, 0, sizeof(float), stream);
    desc_kernel<<<NATC, 256, 0, stream>>>(pos, spe, theta, kn, nidx,
                                          W1, b1, W2, b2, W3, b3, out);
}